// Round 1
// baseline (2594.513 us; speedup 1.0000x reference)
//
#include <hip/hip_runtime.h>
#include <math.h>

#define B_   8
#define C_   256
#define HW_  4096
#define N_   32768   // B_*HW_
#define M_   2024
#define CH_  64
#define INV_TEMP 33.333333333333336f
#define NEPS 1e-12f

__device__ __forceinline__ float wred64(float s) {
#pragma unroll
  for (int off = 32; off > 0; off >>= 1) s += __shfl_xor(s, off, 64);
  return s;
}

__device__ __forceinline__ float dot4(float4 a, float4 b) {
  return a.x * b.x + a.y * b.y + a.z * b.z + a.w * b.w;
}

// ---------------- normalize memory rows (fg rows then bg rows) ----------------
__global__ __launch_bounds__(64) void norm_mem_kernel(
    const float* __restrict__ fg, const float* __restrict__ bg,
    float* __restrict__ fgn, float* __restrict__ bgn) {
  int row = blockIdx.x;  // 0 .. 2*M_-1
  const float* src;
  float* dst;
  if (row < M_) { src = fg + (size_t)row * C_;        dst = fgn + (size_t)row * C_; }
  else          { src = bg + (size_t)(row - M_) * C_; dst = bgn + (size_t)(row - M_) * C_; }
  int lane = threadIdx.x;  // 0..63, 64 lanes * float4 = 256 ch
  float4 v = ((const float4*)src)[lane];
  float s = v.x * v.x + v.y * v.y + v.z * v.z + v.w * v.w;
  s = wred64(s);
  float inv = 1.0f / fmaxf(sqrtf(s), NEPS);
  v.x *= inv; v.y *= inv; v.z *= inv; v.w *= inv;
  ((float4*)dst)[lane] = v;
}

// ---------------- per-pixel inverse L2 norm over channels ----------------
__global__ __launch_bounds__(256) void invnorm_x_kernel(
    const float* __restrict__ feats, float* __restrict__ invn) {
  __shared__ float part[4][64];
  int t = threadIdx.x, lane = t & 63, w = t >> 6;
  int n0 = blockIdx.x * 64;           // 512 blocks * 64 pixels
  int b = n0 >> 12, hw0 = n0 & 4095;  // 64-pixel tile never crosses batch
  const float* p = feats + (size_t)b * C_ * HW_ + hw0 + lane;
  float s = 0.f;
#pragma unroll 8
  for (int i = 0; i < 64; ++i) {      // this wave's 64 channels
    float v = p[(size_t)(w * 64 + i) * HW_];
    s += v * v;
  }
  part[w][lane] = s;
  __syncthreads();
  if (t < 64) {
    float tot = part[0][t] + part[1][t] + part[2][t] + part[3][t];
    invn[n0 + t] = 1.0f / fmaxf(sqrtf(tot), NEPS);
  }
}

// ------- build xn [N,C] (transposed) and initialize out = xn^T (= feats*invn) -------
__global__ __launch_bounds__(256) void xn_out_kernel(
    const float* __restrict__ feats, const float* __restrict__ invn,
    float* __restrict__ xn, float* __restrict__ out) {
  __shared__ float tile[64][65];
  int ct = blockIdx.x & 3, hwt = (blockIdx.x >> 2) & 63, b = blockIdx.x >> 8;
  int c0 = ct * 64, hw0 = hwt * 64;
  int t = threadIdx.x;
  int hwl = t & 63, cw = t >> 6;  // wave cw handles 16 c-rows
  size_t base = (size_t)b * C_ * HW_;
  int n0 = b * HW_ + hw0;
  float iv = invn[n0 + hwl];
#pragma unroll 4
  for (int i = 0; i < 16; ++i) {
    int cl = cw * 16 + i;
    float v = feats[base + (size_t)(c0 + cl) * HW_ + hw0 + hwl] * iv;
    out[base + (size_t)(c0 + cl) * HW_ + hw0 + hwl] = v;  // out init = xn^T
    tile[cl][hwl] = v;
  }
  __syncthreads();
  int cl = t & 63, hp = t >> 6;
#pragma unroll 4
  for (int i = 0; i < 16; ++i) {
    int hh = hp * 16 + i;
    xn[(size_t)(n0 + hh) * C_ + c0 + cl] = tile[cl][hh];
  }
}

// ---------------- gates: g = sigmoid(relu(xn@w1+b1)@w2+b2), both fg and bg ----------------
__global__ __launch_bounds__(256) void gate_kernel(
    const float* __restrict__ xn,
    const float* __restrict__ w1f, const float* __restrict__ b1f,
    const float* __restrict__ w2f, const float* __restrict__ b2f,
    const float* __restrict__ w1b, const float* __restrict__ b1b,
    const float* __restrict__ w2b, const float* __restrict__ b2b,
    float* __restrict__ gf, float* __restrict__ gb) {
  __shared__ float xr[4][C_];
  int t = threadIdx.x;
  int w = t >> 6, lane = t & 63;
  int n = blockIdx.x * 4 + w;  // wave per pixel
  float4 v = ((const float4*)(xn + (size_t)n * C_))[lane];
  *(float4*)&xr[w][lane * 4] = v;
  __syncthreads();
  float hf = b1f[lane], hb = b1b[lane];
#pragma unroll 8
  for (int c = 0; c < C_; ++c) {
    float x = xr[w][c];  // LDS broadcast
    hf += x * w1f[c * CH_ + lane];
    hb += x * w1b[c * CH_ + lane];
  }
  hf = fmaxf(hf, 0.f);
  hb = fmaxf(hb, 0.f);
  float sf = hf * w2f[lane], sb = hb * w2b[lane];
  sf = wred64(sf);
  sb = wred64(sb);
  if (lane == 0) {
    gf[n] = 1.f / (1.f + __expf(-(sf + b2f[0])));
    gb[n] = 1.f / (1.f + __expf(-(sb + b2b[0])));
  }
}

// ---------------- flash attention over memory; out += sign * g * softmax(xn@memn^T/T) @ memn ----------------
// 64 rows/block, m-chunks of 64, c-chunks of 64. No max-subtraction needed:
// |logit| <= 1/0.03 = 33.3, exp and 2024-term sum safely inside fp32 range.
__global__ __launch_bounds__(256) void flash_kernel(
    const float* __restrict__ xn, const float* __restrict__ memn,
    const float* __restrict__ g, float* __restrict__ out, float sign) {
  __shared__ float xs[64][68];
  __shared__ float ms[64][68];
  __shared__ float pt[64][68];   // P transposed: pt[m][r]
  __shared__ float rowsum[64];
  int t = threadIdx.x;
  int mq = t & 15, rq = t >> 4;  // rq 0..15
  int r0 = rq * 4;
  // thread's 4 m rows are mq, mq+16, mq+32, mq+48 (stride-16 -> 2-way banks, free)
  int row0 = blockIdx.x * 64;

  if (t < 64) rowsum[t] = 0.f;
  float acc[4][16];  // [row i][c = cc*4+k], c_global = cc*64 + mq*4 + k
#pragma unroll
  for (int i = 0; i < 4; ++i)
#pragma unroll
    for (int k = 0; k < 16; ++k) acc[i][k] = 0.f;
  __syncthreads();

  const int NCH = (M_ + 63) / 64;  // 32 (last chunk has 40 valid rows)
  for (int mc = 0; mc < NCH; ++mc) {
    int mbase = mc * 64;
    float S[4][4];
#pragma unroll
    for (int i = 0; i < 4; ++i)
#pragma unroll
      for (int j = 0; j < 4; ++j) S[i][j] = 0.f;

    // ---- S = xn_tile @ mem_chunk^T ----
#pragma unroll
    for (int cc = 0; cc < 4; ++cc) {
      // stage xs and ms for this c-chunk
#pragma unroll
      for (int j = 0; j < 4; ++j) {
        int sr = j * 16 + rq;
        *(float4*)&xs[sr][mq * 4] =
            *(const float4*)&xn[(size_t)(row0 + sr) * C_ + cc * 64 + mq * 4];
        int m = mbase + sr;
        float4 bv = make_float4(0.f, 0.f, 0.f, 0.f);
        if (m < M_) bv = *(const float4*)&memn[(size_t)m * C_ + cc * 64 + mq * 4];
        *(float4*)&ms[sr][mq * 4] = bv;
      }
      __syncthreads();
#pragma unroll 4
      for (int cq = 0; cq < 16; ++cq) {
        float4 a0 = *(const float4*)&xs[r0 + 0][cq * 4];
        float4 a1 = *(const float4*)&xs[r0 + 1][cq * 4];
        float4 a2 = *(const float4*)&xs[r0 + 2][cq * 4];
        float4 a3 = *(const float4*)&xs[r0 + 3][cq * 4];
        float4 b0 = *(const float4*)&ms[mq + 0][cq * 4];
        float4 b1 = *(const float4*)&ms[mq + 16][cq * 4];
        float4 b2 = *(const float4*)&ms[mq + 32][cq * 4];
        float4 b3 = *(const float4*)&ms[mq + 48][cq * 4];
        S[0][0] += dot4(a0, b0); S[0][1] += dot4(a0, b1);
        S[0][2] += dot4(a0, b2); S[0][3] += dot4(a0, b3);
        S[1][0] += dot4(a1, b0); S[1][1] += dot4(a1, b1);
        S[1][2] += dot4(a1, b2); S[1][3] += dot4(a1, b3);
        S[2][0] += dot4(a2, b0); S[2][1] += dot4(a2, b1);
        S[2][2] += dot4(a2, b2); S[2][3] += dot4(a2, b3);
        S[3][0] += dot4(a3, b0); S[3][1] += dot4(a3, b1);
        S[3][2] += dot4(a3, b2); S[3][3] += dot4(a3, b3);
      }
      __syncthreads();
    }

    // ---- P = exp(S/T) (unnormalized), accumulate row sums, write P^T to LDS ----
    float P[4][4];
    float pr[4] = {0.f, 0.f, 0.f, 0.f};
#pragma unroll
    for (int i = 0; i < 4; ++i)
#pragma unroll
      for (int j = 0; j < 4; ++j) {
        float pp = __expf(S[i][j] * INV_TEMP);
        if (mbase + mq + 16 * j >= M_) pp = 0.f;  // tail mask
        P[i][j] = pp;
        pr[i] += pp;
      }
    // reduce partial row sums across the 16 mq lanes of this rq group
#pragma unroll
    for (int off = 1; off < 16; off <<= 1) {
#pragma unroll
      for (int i = 0; i < 4; ++i) pr[i] += __shfl_xor(pr[i], off, 64);
    }
    if (mq == 0) {
#pragma unroll
      for (int i = 0; i < 4; ++i) atomicAdd(&rowsum[r0 + i], pr[i]);
    }
#pragma unroll
    for (int j = 0; j < 4; ++j) {
      float4 col = make_float4(P[0][j], P[1][j], P[2][j], P[3][j]);
      *(float4*)&pt[mq + 16 * j][r0] = col;
    }
    __syncthreads();

    // ---- acc += P @ mem_chunk ----
#pragma unroll
    for (int cc = 0; cc < 4; ++cc) {
#pragma unroll
      for (int j = 0; j < 4; ++j) {
        int sr = j * 16 + rq;
        int m = mbase + sr;
        float4 bv = make_float4(0.f, 0.f, 0.f, 0.f);
        if (m < M_) bv = *(const float4*)&memn[(size_t)m * C_ + cc * 64 + mq * 4];
        *(float4*)&ms[sr][mq * 4] = bv;
      }
      __syncthreads();
#pragma unroll 4
      for (int m = 0; m < 64; ++m) {
        float4 pv = *(const float4*)&pt[m][r0];
        float4 bv = *(const float4*)&ms[m][mq * 4];
        acc[0][cc * 4 + 0] += pv.x * bv.x; acc[0][cc * 4 + 1] += pv.x * bv.y;
        acc[0][cc * 4 + 2] += pv.x * bv.z; acc[0][cc * 4 + 3] += pv.x * bv.w;
        acc[1][cc * 4 + 0] += pv.y * bv.x; acc[1][cc * 4 + 1] += pv.y * bv.y;
        acc[1][cc * 4 + 2] += pv.y * bv.z; acc[1][cc * 4 + 3] += pv.y * bv.w;
        acc[2][cc * 4 + 0] += pv.z * bv.x; acc[2][cc * 4 + 1] += pv.z * bv.y;
        acc[2][cc * 4 + 2] += pv.z * bv.z; acc[2][cc * 4 + 3] += pv.z * bv.w;
        acc[3][cc * 4 + 0] += pv.w * bv.x; acc[3][cc * 4 + 1] += pv.w * bv.y;
        acc[3][cc * 4 + 2] += pv.w * bv.z; acc[3][cc * 4 + 3] += pv.w * bv.w;
      }
      __syncthreads();
    }
  }

  // ---- epilogue: out[b, c, hw] += sign * g[n] * acc / rowsum, via LDS transpose ----
  int bb = row0 >> 12, hwb = row0 & 4095;
  float sc[4];
#pragma unroll
  for (int i = 0; i < 4; ++i)
    sc[i] = sign * g[row0 + r0 + i] / rowsum[r0 + i];

#pragma unroll
  for (int cc = 0; cc < 4; ++cc) {
#pragma unroll
    for (int i = 0; i < 4; ++i)
#pragma unroll
      for (int k = 0; k < 4; ++k)
        xs[mq * 4 + k][r0 + i] = sc[i] * acc[i][cc * 4 + k];  // reuse xs as trans tile
    __syncthreads();
    int rl = t & 63, cb = (t >> 6) * 16;
    size_t obase = (size_t)bb * C_ * HW_ + hwb + rl;
#pragma unroll 4
    for (int i2 = 0; i2 < 16; ++i2) {
      int cl = cb + i2;
      size_t a = obase + (size_t)(cc * 64 + cl) * HW_;
      out[a] += xs[cl][rl];
    }
    __syncthreads();
  }
}

extern "C" void kernel_launch(void* const* d_in, const int* in_sizes, int n_in,
                              void* d_out, int out_size, void* d_ws, size_t ws_size,
                              hipStream_t stream) {
  const float* feats = (const float*)d_in[0];
  const float* fg    = (const float*)d_in[1];
  const float* bg    = (const float*)d_in[2];
  const float* w1f   = (const float*)d_in[3];
  const float* b1f   = (const float*)d_in[4];
  const float* w2f   = (const float*)d_in[5];
  const float* b2f   = (const float*)d_in[6];
  const float* w1b   = (const float*)d_in[7];
  const float* b1b   = (const float*)d_in[8];
  const float* w2b   = (const float*)d_in[9];
  const float* b2b   = (const float*)d_in[10];
  float* out = (float*)d_out;

  float* ws   = (float*)d_ws;
  float* xn   = ws;                          // N_*C_
  float* fgn  = xn + (size_t)N_ * C_;        // M_*C_
  float* bgn  = fgn + (size_t)M_ * C_;       // M_*C_
  float* gf   = bgn + (size_t)M_ * C_;       // N_
  float* gb   = gf + N_;                     // N_
  float* invn = gb + N_;                     // N_

  norm_mem_kernel<<<2 * M_, 64, 0, stream>>>(fg, bg, fgn, bgn);
  invnorm_x_kernel<<<N_ / 64, 256, 0, stream>>>(feats, invn);
  xn_out_kernel<<<2048, 256, 0, stream>>>(feats, invn, xn, out);
  gate_kernel<<<N_ / 4, 256, 0, stream>>>(xn, w1f, b1f, w2f, b2f,
                                          w1b, b1b, w2b, b2b, gf, gb);
  flash_kernel<<<N_ / 64, 256, 0, stream>>>(xn, fgn, gf, out, 1.0f);
  flash_kernel<<<N_ / 64, 256, 0, stream>>>(xn, bgn, gb, out, -1.0f);
}

// Round 2
// 1040.626 us; speedup vs baseline: 2.4932x; 2.4932x over previous
//
#include <hip/hip_runtime.h>
#include <math.h>

#define B_   8
#define C_   256
#define HW_  4096
#define N_   32768   // B_*HW_
#define M_   2024
#define MP_  2048    // M padded to multiple of 64
#define CH_  64
#define INV_TEMP 33.333333333333336f
#define NEPS 1e-12f

typedef __attribute__((ext_vector_type(8))) short short8;   // 8 x bf16 (4 VGPRs)
typedef __attribute__((ext_vector_type(4))) float floatx4;  // MFMA accumulator

__device__ __forceinline__ float wred64(float s) {
#pragma unroll
  for (int off = 32; off > 0; off >>= 1) s += __shfl_xor(s, off, 64);
  return s;
}

__device__ __forceinline__ unsigned short f2bf(float f) {
  union { float f; unsigned u; } v; v.f = f;
  unsigned r = v.u + 0x7FFFu + ((v.u >> 16) & 1u);  // RNE, finite inputs only
  return (unsigned short)(r >> 16);
}
__device__ __forceinline__ float bf2f(unsigned short b) {
  union { unsigned u; float f; } v; v.u = ((unsigned)b) << 16; return v.f;
}

// ------- normalize memory rows -> bf16 [MP_][C_] and transposed bf16 [C_][MP_] -------
__global__ __launch_bounds__(64) void norm_mem_kernel(
    const float* __restrict__ fg, const float* __restrict__ bg,
    unsigned short* __restrict__ fgb, unsigned short* __restrict__ bgb,
    unsigned short* __restrict__ fgT, unsigned short* __restrict__ bgT) {
  int row = blockIdx.x;  // 0..2*MP_-1
  const float* src; unsigned short *mb, *mt; int r;
  if (row < MP_) { r = row;       src = fg; mb = fgb; mt = fgT; }
  else           { r = row - MP_; src = bg; mb = bgb; mt = bgT; }
  int lane = threadIdx.x;  // 64 lanes * 4 ch = 256
  if (r >= M_) {  // zero padding rows (ws is poisoned 0xAA)
    ushort4 z = {0, 0, 0, 0};
    *(ushort4*)&mb[(size_t)r * C_ + lane * 4] = z;
#pragma unroll
    for (int j = 0; j < 4; ++j) mt[(size_t)(lane * 4 + j) * MP_ + r] = 0;
    return;
  }
  float4 v = ((const float4*)(src + (size_t)r * C_))[lane];
  float s = v.x * v.x + v.y * v.y + v.z * v.z + v.w * v.w;
  s = wred64(s);
  float inv = 1.0f / fmaxf(sqrtf(s), NEPS);
  ushort4 o;
  o.x = f2bf(v.x * inv); o.y = f2bf(v.y * inv);
  o.z = f2bf(v.z * inv); o.w = f2bf(v.w * inv);
  *(ushort4*)&mb[(size_t)r * C_ + lane * 4] = o;
  mt[(size_t)(lane * 4 + 0) * MP_ + r] = o.x;
  mt[(size_t)(lane * 4 + 1) * MP_ + r] = o.y;
  mt[(size_t)(lane * 4 + 2) * MP_ + r] = o.z;
  mt[(size_t)(lane * 4 + 3) * MP_ + r] = o.w;
}

// ---------------- per-pixel inverse L2 norm over channels ----------------
__global__ __launch_bounds__(256) void invnorm_x_kernel(
    const float* __restrict__ feats, float* __restrict__ invn) {
  __shared__ float part[4][64];
  int t = threadIdx.x, lane = t & 63, w = t >> 6;
  int n0 = blockIdx.x * 64;
  int b = n0 >> 12, hw0 = n0 & 4095;
  const float* p = feats + (size_t)b * C_ * HW_ + hw0 + lane;
  float s = 0.f;
#pragma unroll 8
  for (int i = 0; i < 64; ++i) {
    float v = p[(size_t)(w * 64 + i) * HW_];
    s += v * v;
  }
  part[w][lane] = s;
  __syncthreads();
  if (t < 64) {
    float tot = part[0][t] + part[1][t] + part[2][t] + part[3][t];
    invn[n0 + t] = 1.0f / fmaxf(sqrtf(tot), NEPS);
  }
}

// ------- build xnb bf16 [N,C] and initialize out = xn^T (fp32, NCHW) -------
__global__ __launch_bounds__(256) void xn_out_kernel(
    const float* __restrict__ feats, const float* __restrict__ invn,
    unsigned short* __restrict__ xnb, float* __restrict__ out) {
  __shared__ float tile[64][65];
  int ct = blockIdx.x & 3, hwt = (blockIdx.x >> 2) & 63, b = blockIdx.x >> 8;
  int c0 = ct * 64, hw0 = hwt * 64;
  int t = threadIdx.x;
  int hwl = t & 63, cw = t >> 6;
  size_t base = (size_t)b * C_ * HW_;
  int n0 = b * HW_ + hw0;
  float iv = invn[n0 + hwl];
#pragma unroll 4
  for (int i = 0; i < 16; ++i) {
    int cl = cw * 16 + i;
    float v = feats[base + (size_t)(c0 + cl) * HW_ + hw0 + hwl] * iv;
    out[base + (size_t)(c0 + cl) * HW_ + hw0 + hwl] = v;  // out init = xn^T
    tile[cl][hwl] = v;
  }
  __syncthreads();
  int cl = t & 63, hp = t >> 6;
#pragma unroll 4
  for (int i = 0; i < 16; ++i) {
    int hh = hp * 16 + i;
    xnb[(size_t)(n0 + hh) * C_ + c0 + cl] = f2bf(tile[cl][hh]);
  }
}

// ---------------- gates from bf16 xn ----------------
__global__ __launch_bounds__(256) void gate_kernel(
    const unsigned short* __restrict__ xnb,
    const float* __restrict__ w1f, const float* __restrict__ b1f,
    const float* __restrict__ w2f, const float* __restrict__ b2f,
    const float* __restrict__ w1b, const float* __restrict__ b1b,
    const float* __restrict__ w2b, const float* __restrict__ b2b,
    float* __restrict__ gf, float* __restrict__ gb) {
  __shared__ float xr[4][C_];
  int t = threadIdx.x;
  int w = t >> 6, lane = t & 63;
  int n = blockIdx.x * 4 + w;
  ushort4 u = *(const ushort4*)&xnb[(size_t)n * C_ + lane * 4];
  xr[w][lane * 4 + 0] = bf2f(u.x);
  xr[w][lane * 4 + 1] = bf2f(u.y);
  xr[w][lane * 4 + 2] = bf2f(u.z);
  xr[w][lane * 4 + 3] = bf2f(u.w);
  __syncthreads();
  float hf = b1f[lane], hb = b1b[lane];
#pragma unroll 8
  for (int c = 0; c < C_; ++c) {
    float x = xr[w][c];
    hf += x * w1f[c * CH_ + lane];
    hb += x * w1b[c * CH_ + lane];
  }
  hf = fmaxf(hf, 0.f);
  hb = fmaxf(hb, 0.f);
  float sf = hf * w2f[lane], sb = hb * w2b[lane];
  sf = wred64(sf);
  sb = wred64(sb);
  if (lane == 0) {
    gf[n] = 1.f / (1.f + __expf(-(sf + b2f[0])));
    gb[n] = 1.f / (1.f + __expf(-(sb + b2b[0])));
  }
}

// ---------------- MFMA flash attention over memory ----------------
// Block: 64 pixels, 4 waves. S-phase: wave w = rows [16w,16w+16) x all 64 m,
// A-frags in registers, B-frags direct from global memb (exact B-layout).
// PV: wave w = all 64 rows x C-slice [64w, 64w+64), P via LDS round-trip,
// B-frags direct from global membT (m-fast). Unnormalized exp (|logit|<=33.3),
// rowsum in registers, one barrier per m-chunk (double-buffered P).
__global__ __launch_bounds__(256, 2) void flash_kernel(
    const unsigned short* __restrict__ xnb,
    const unsigned short* __restrict__ memb,   // [MP_][C_]
    const unsigned short* __restrict__ membT,  // [C_][MP_]
    const float* __restrict__ g,
    float* __restrict__ out, float sign) {
  __shared__ char smem[19456];
  unsigned short* Pb0 = (unsigned short*)smem;           // [64][72] bf16 = 9216 B
  unsigned short* Pb1 = (unsigned short*)(smem + 9216);  // second buffer
  float* rowsum = (float*)(smem + 18432);                // [64]
  float* comb   = (float*)(smem + 18688);                // [64]
  float* trans  = (float*)smem;                          // [64][66] f32 epilogue (aliases Pb)

  int t = threadIdx.x;
  int w = t >> 6, l = t & 63;
  int lm = l & 15, quad = l >> 4;
  int row0 = blockIdx.x * 64;

  // A-frags: wave w rows 16w+lm, k = kb*32 + quad*8 + j
  short8 afrag[8];
  {
    size_t ab = (size_t)(row0 + 16 * w + lm) * C_ + quad * 8;
#pragma unroll
    for (int kb = 0; kb < 8; ++kb)
      afrag[kb] = *(const short8*)&xnb[ab + kb * 32];
  }

  floatx4 accO[4][4];  // [rt][ct]
#pragma unroll
  for (int rt = 0; rt < 4; ++rt)
#pragma unroll
    for (int ct = 0; ct < 4; ++ct)
      accO[rt][ct] = (floatx4){0.f, 0.f, 0.f, 0.f};
  float rs[4] = {0.f, 0.f, 0.f, 0.f};

  for (int mc = 0; mc < MP_ / 64; ++mc) {
    int mb0 = mc * 64;

    // ---- S = Q @ mem^T (rows 16w..16w+15, m mb0..mb0+63) ----
    floatx4 accS[4];
#pragma unroll
    for (int mt = 0; mt < 4; ++mt) accS[mt] = (floatx4){0.f, 0.f, 0.f, 0.f};
#pragma unroll
    for (int mt = 0; mt < 4; ++mt) {
      size_t bidx = (size_t)(mb0 + mt * 16 + lm) * C_ + quad * 8;
#pragma unroll
      for (int kb = 0; kb < 8; ++kb) {
        short8 bfrag = *(const short8*)&memb[bidx + kb * 32];
        accS[mt] = __builtin_amdgcn_mfma_f32_16x16x32_bf16(afrag[kb], bfrag, accS[mt], 0, 0, 0);
      }
    }

    // ---- P = exp(S/T) -> bf16, rowsum from rounded P, write to LDS [row][m] ----
    unsigned short* P = (mc & 1) ? Pb1 : Pb0;
#pragma unroll
    for (int mt = 0; mt < 4; ++mt) {
      int m = mb0 + mt * 16 + lm;
      bool valid = (m < M_);
#pragma unroll
      for (int r = 0; r < 4; ++r) {
        float p = valid ? __expf(accS[mt][r] * INV_TEMP) : 0.f;
        unsigned short pb = f2bf(p);
        rs[r] += bf2f(pb);
        P[(16 * w + quad * 4 + r) * 72 + mt * 16 + lm] = pb;
      }
    }
    __syncthreads();

    // ---- O += P @ mem (all 64 rows, C-slice 64w..64w+63) ----
    short8 pfrag[4][2];
#pragma unroll
    for (int rt = 0; rt < 4; ++rt)
#pragma unroll
      for (int kb2 = 0; kb2 < 2; ++kb2)
        pfrag[rt][kb2] = *(const short8*)&P[(rt * 16 + lm) * 72 + kb2 * 32 + quad * 8];
#pragma unroll
    for (int ct = 0; ct < 4; ++ct) {
      int c = w * 64 + ct * 16 + lm;
      size_t tb = (size_t)c * MP_ + mb0 + quad * 8;
      short8 bf0 = *(const short8*)&membT[tb];
      short8 bf1 = *(const short8*)&membT[tb + 32];
#pragma unroll
      for (int rt = 0; rt < 4; ++rt) {
        accO[rt][ct] = __builtin_amdgcn_mfma_f32_16x16x32_bf16(pfrag[rt][0], bf0, accO[rt][ct], 0, 0, 0);
        accO[rt][ct] = __builtin_amdgcn_mfma_f32_16x16x32_bf16(pfrag[rt][1], bf1, accO[rt][ct], 0, 0, 0);
      }
    }
  }

  // ---- epilogue: rowsum finalize, scale, transpose, coalesced out += ----
#pragma unroll
  for (int off = 1; off < 16; off <<= 1)
#pragma unroll
    for (int r = 0; r < 4; ++r) rs[r] += __shfl_xor(rs[r], off, 64);
  if (lm == 0) {
#pragma unroll
    for (int r = 0; r < 4; ++r) rowsum[16 * w + quad * 4 + r] = rs[r];
  }
  __syncthreads();
  if (t < 64) comb[t] = sign * g[row0 + t] / rowsum[t];
  __syncthreads();

  int bb = row0 >> 12, hw0 = row0 & 4095;
#pragma unroll 1
  for (int ct = 0; ct < 4; ++ct) {
#pragma unroll
    for (int rt = 0; rt < 4; ++rt)
#pragma unroll
      for (int r = 0; r < 4; ++r) {
        int rowi = rt * 16 + quad * 4 + r;
        trans[rowi * 66 + w * 16 + lm] = comb[rowi] * accO[rt][ct][r];
      }
    __syncthreads();
    int hw = t & 63, cw2 = t >> 6;
    size_t ob = (size_t)bb * C_ * HW_ + hw0 + hw;
#pragma unroll 4
    for (int i = 0; i < 16; ++i) {
      int cs = cw2 * 16 + i;              // trans column
      int cg = cw2 * 64 + ct * 16 + i;    // global channel
      out[ob + (size_t)cg * HW_] += trans[hw * 66 + cs];
    }
    __syncthreads();
  }
}

extern "C" void kernel_launch(void* const* d_in, const int* in_sizes, int n_in,
                              void* d_out, int out_size, void* d_ws, size_t ws_size,
                              hipStream_t stream) {
  const float* feats = (const float*)d_in[0];
  const float* fg    = (const float*)d_in[1];
  const float* bg    = (const float*)d_in[2];
  const float* w1f   = (const float*)d_in[3];
  const float* b1f   = (const float*)d_in[4];
  const float* w2f   = (const float*)d_in[5];
  const float* b2f   = (const float*)d_in[6];
  const float* w1b   = (const float*)d_in[7];
  const float* b1b   = (const float*)d_in[8];
  const float* w2b   = (const float*)d_in[9];
  const float* b2b   = (const float*)d_in[10];
  float* out = (float*)d_out;

  char* ws = (char*)d_ws;
  unsigned short* xnb = (unsigned short*)ws;                 // N_*C_ bf16 = 16 MB
  unsigned short* fgb = xnb + (size_t)N_ * C_;               // MP_*C_
  unsigned short* bgb = fgb + (size_t)MP_ * C_;
  unsigned short* fgT = bgb + (size_t)MP_ * C_;              // C_*MP_
  unsigned short* bgT = fgT + (size_t)C_ * MP_;
  float* gf   = (float*)(bgT + (size_t)C_ * MP_);            // N_
  float* gb   = gf + N_;                                     // N_
  float* invn = gb + N_;                                     // N_

  norm_mem_kernel<<<2 * MP_, 64, 0, stream>>>(fg, bg, fgb, bgb, fgT, bgT);
  invnorm_x_kernel<<<N_ / 64, 256, 0, stream>>>(feats, invn);
  xn_out_kernel<<<2048, 256, 0, stream>>>(feats, invn, xnb, out);
  gate_kernel<<<N_ / 4, 256, 0, stream>>>(xnb, w1f, b1f, w2f, b2f,
                                          w1b, b1b, w2b, b2b, gf, gb);
  flash_kernel<<<N_ / 64, 256, 0, stream>>>(xnb, fgb, fgT, gf, out, 1.0f);
  flash_kernel<<<N_ / 64, 256, 0, stream>>>(xnb, bgb, bgT, gb, out, -1.0f);
}

// Round 3
// 811.649 us; speedup vs baseline: 3.1966x; 1.2821x over previous
//
#include <hip/hip_runtime.h>
#include <math.h>

#define B_   8
#define C_   256
#define HW_  4096
#define N_   32768   // B_*HW_
#define M_   2024
#define MP_  2048    // M padded to multiple of 64
#define CH_  64
#define INV_TEMP 33.333333333333336f
#define NEPS 1e-12f

typedef __attribute__((ext_vector_type(8))) short short8;   // 8 x bf16 (4 VGPRs)
typedef __attribute__((ext_vector_type(4))) float floatx4;  // MFMA accumulator

__device__ __forceinline__ float wred64(float s) {
#pragma unroll
  for (int off = 32; off > 0; off >>= 1) s += __shfl_xor(s, off, 64);
  return s;
}

__device__ __forceinline__ unsigned short f2bf(float f) {
  union { float f; unsigned u; } v; v.f = f;
  unsigned r = v.u + 0x7FFFu + ((v.u >> 16) & 1u);  // RNE, finite inputs only
  return (unsigned short)(r >> 16);
}
__device__ __forceinline__ float bf2f(unsigned short b) {
  union { unsigned u; float f; } v; v.u = ((unsigned)b) << 16; return v.f;
}

// ------- normalize memory rows -> bf16 [MP_][C_] AND bf16-transposed [C_][MP_] -------
// Block = 64 memory rows. LDS-transposed so membT writes are 128 B contiguous
// (previous version did scattered 2 B stores -> 32x write amplification).
__global__ __launch_bounds__(256) void norm_mem_kernel(
    const float* __restrict__ fg, const float* __restrict__ bg,
    unsigned short* __restrict__ fgb, unsigned short* __restrict__ bgb,
    unsigned short* __restrict__ fgT, unsigned short* __restrict__ bgT) {
  __shared__ unsigned short tile[64][258];  // stride 258 -> 2-way banks on transpose read (free)
  int bid = blockIdx.x;  // 0..63: 32 fg tiles then 32 bg tiles
  const float* src; unsigned short *mb, *mt; int r0;
  if (bid < 32) { src = fg; mb = fgb; mt = fgT; r0 = bid * 64; }
  else          { src = bg; mb = bgb; mt = bgT; r0 = (bid - 32) * 64; }
  int t = threadIdx.x;
  int rr = t >> 2, c4 = t & 3;  // row r0+rr, channel quarter c4 (64 ch each)
  int row = r0 + rr;
  float v[64];
  float s = 0.f;
  if (row < M_) {
    const float4* p = (const float4*)(src + (size_t)row * C_ + c4 * 64);
#pragma unroll
    for (int i = 0; i < 16; ++i) {
      float4 q = p[i];
      v[i * 4 + 0] = q.x; v[i * 4 + 1] = q.y; v[i * 4 + 2] = q.z; v[i * 4 + 3] = q.w;
      s += q.x * q.x + q.y * q.y + q.z * q.z + q.w * q.w;
    }
  } else {
#pragma unroll
    for (int i = 0; i < 64; ++i) v[i] = 0.f;  // zero padding rows (m >= M_)
  }
  s += __shfl_xor(s, 1, 64);
  s += __shfl_xor(s, 2, 64);
  float inv = (row < M_) ? 1.0f / fmaxf(sqrtf(s), NEPS) : 0.f;
#pragma unroll
  for (int i = 0; i < 16; ++i) {
    ushort4 o;
    o.x = f2bf(v[i * 4 + 0] * inv); o.y = f2bf(v[i * 4 + 1] * inv);
    o.z = f2bf(v[i * 4 + 2] * inv); o.w = f2bf(v[i * 4 + 3] * inv);
    *(ushort4*)&mb[(size_t)row * C_ + c4 * 64 + i * 4] = o;
    *(ushort4*)&tile[rr][c4 * 64 + i * 4] = o;
  }
  __syncthreads();
  int m = t & 63, cw = t >> 6;
#pragma unroll 8
  for (int j = 0; j < 64; ++j) {
    int c = cw * 64 + j;
    mt[(size_t)c * MP_ + r0 + m] = tile[m][c];  // 64 consecutive m -> 128 B contiguous
  }
}

// ---------------- per-pixel inverse L2 norm over channels ----------------
__global__ __launch_bounds__(256) void invnorm_x_kernel(
    const float* __restrict__ feats, float* __restrict__ invn) {
  __shared__ float part[4][64];
  int t = threadIdx.x, lane = t & 63, w = t >> 6;
  int n0 = blockIdx.x * 64;
  int b = n0 >> 12, hw0 = n0 & 4095;
  const float* p = feats + (size_t)b * C_ * HW_ + hw0 + lane;
  float s = 0.f;
#pragma unroll 8
  for (int i = 0; i < 64; ++i) {
    float v = p[(size_t)(w * 64 + i) * HW_];
    s += v * v;
  }
  part[w][lane] = s;
  __syncthreads();
  if (t < 64) {
    float tot = part[0][t] + part[1][t] + part[2][t] + part[3][t];
    invn[n0 + t] = 1.0f / fmaxf(sqrtf(tot), NEPS);
  }
}

// ------- build xnb bf16 [N,C] (pixel-major) from feats (channel-major) -------
__global__ __launch_bounds__(256) void xnb_kernel(
    const float* __restrict__ feats, const float* __restrict__ invn,
    unsigned short* __restrict__ xnb) {
  __shared__ float tile[64][65];
  int ct = blockIdx.x & 3, hwt = (blockIdx.x >> 2) & 63, b = blockIdx.x >> 8;
  int c0 = ct * 64, hw0 = hwt * 64;
  int t = threadIdx.x;
  int hwl = t & 63, cw = t >> 6;
  size_t base = (size_t)b * C_ * HW_;
  int n0 = b * HW_ + hw0;
  float iv = invn[n0 + hwl];
#pragma unroll 4
  for (int i = 0; i < 16; ++i) {
    int cl = cw * 16 + i;
    tile[cl][hwl] = feats[base + (size_t)(c0 + cl) * HW_ + hw0 + hwl] * iv;
  }
  __syncthreads();
  int cl = t & 63, hp = t >> 6;
#pragma unroll 4
  for (int i = 0; i < 16; ++i) {
    int hh = hp * 16 + i;
    xnb[(size_t)(n0 + hh) * C_ + c0 + cl] = f2bf(tile[cl][hh]);
  }
}

// ---------------- gates: 16 pixels per block (weights reused 16x) ----------------
__global__ __launch_bounds__(256) void gate_kernel(
    const unsigned short* __restrict__ xnb,
    const float* __restrict__ w1f, const float* __restrict__ b1f,
    const float* __restrict__ w2f, const float* __restrict__ b2f,
    const float* __restrict__ w1b, const float* __restrict__ b1b,
    const float* __restrict__ w2b, const float* __restrict__ b2b,
    float* __restrict__ gf, float* __restrict__ gb) {
  __shared__ float xr[16][C_];
  int t = threadIdx.x, w = t >> 6, lane = t & 63;
  int n0 = blockIdx.x * 16;
#pragma unroll
  for (int pp = 0; pp < 4; ++pp) {
    int px = w * 4 + pp;
    ushort4 u = *(const ushort4*)&xnb[(size_t)(n0 + px) * C_ + lane * 4];
    xr[px][lane * 4 + 0] = bf2f(u.x);
    xr[px][lane * 4 + 1] = bf2f(u.y);
    xr[px][lane * 4 + 2] = bf2f(u.z);
    xr[px][lane * 4 + 3] = bf2f(u.w);
  }
  __syncthreads();
  float hf[4], hb[4];
#pragma unroll
  for (int pp = 0; pp < 4; ++pp) { hf[pp] = b1f[lane]; hb[pp] = b1b[lane]; }
#pragma unroll 4
  for (int c = 0; c < C_; ++c) {
    float wf = w1f[c * CH_ + lane];
    float wb = w1b[c * CH_ + lane];
#pragma unroll
    for (int pp = 0; pp < 4; ++pp) {
      float x = xr[w * 4 + pp][c];  // LDS broadcast
      hf[pp] += x * wf;
      hb[pp] += x * wb;
    }
  }
  float b2fv = b2f[0], b2bv = b2b[0];
#pragma unroll
  for (int pp = 0; pp < 4; ++pp) {
    float sf = fmaxf(hf[pp], 0.f) * w2f[lane];
    float sb = fmaxf(hb[pp], 0.f) * w2b[lane];
    sf = wred64(sf);
    sb = wred64(sb);
    if (lane == 0) {
      gf[n0 + w * 4 + pp] = 1.f / (1.f + __expf(-(sf + b2fv)));
      gb[n0 + w * 4 + pp] = 1.f / (1.f + __expf(-(sb + b2bv)));
    }
  }
}

// ---------------- fused MFMA flash attention: fg and bg in one kernel ----------------
// Block: 64 pixels, 8 waves (512 threads). Per pass:
//   S-phase: wave (rg = w&3, mh = w>>2): rows [16rg,16rg+16) x m-half [32mh,32mh+32).
//            accS[2] (8 regs); A-frags in registers (shared across both passes).
//   PV:      wave w: all 64 rows x C-slice [32w, 32w+32). accO[4][2] = 32 regs.
// fg result rescaled into res registers, bg pass subtracts. Epilogue writes
// out = feats*invn + res exactly once (no RMW, no init kernel).
// Per-thread live state ~150 VGPR -> no scratch spill (round-2 killer: 1.1 GB
// of per-chunk accO spill writebacks).
__global__ __launch_bounds__(512, 2) void flash_fused_kernel(
    const unsigned short* __restrict__ xnb,
    const unsigned short* __restrict__ fgb, const unsigned short* __restrict__ fgT,
    const unsigned short* __restrict__ bgb, const unsigned short* __restrict__ bgT,
    const float* __restrict__ gf, const float* __restrict__ gb,
    const float* __restrict__ feats, const float* __restrict__ invn,
    float* __restrict__ out) {
  __shared__ char smem[18944];
  unsigned short* Pb0 = (unsigned short*)smem;            // [64][72] bf16 = 9216 B
  unsigned short* Pb1 = (unsigned short*)(smem + 9216);   // double buffer
  float* rowsum = (float*)(smem + 18432);                 // [64]
  float* comb   = (float*)(smem + 18688);                 // [64]

  int t = threadIdx.x;
  int w = t >> 6, l = t & 63;
  int lm = l & 15, quad = l >> 4;
  int rg = w & 3, mh = w >> 2;
  int row0 = blockIdx.x * 64;

  // A-frags: rows row0 + 16*rg + lm, k = kb*32 + quad*8 + j (waves rg and rg+4 duplicate)
  short8 afrag[8];
  {
    const unsigned short* ap = xnb + (size_t)(row0 + 16 * rg + lm) * C_ + quad * 8;
#pragma unroll
    for (int kb = 0; kb < 8; ++kb)
      afrag[kb] = *(const short8*)(ap + kb * 32);
  }

  floatx4 res[4][2];  // scaled fg - bg result, C/D layout, C-slice [32w,32w+32)
#pragma unroll
  for (int rt = 0; rt < 4; ++rt)
#pragma unroll
    for (int ct = 0; ct < 2; ++ct) res[rt][ct] = (floatx4){0.f, 0.f, 0.f, 0.f};

#pragma unroll
  for (int pass = 0; pass < 2; ++pass) {
    const unsigned short* memb  = pass ? bgb : fgb;
    const unsigned short* membT = pass ? bgT : fgT;
    const float* gp = pass ? gb : gf;

    floatx4 accO[4][2];
#pragma unroll
    for (int rt = 0; rt < 4; ++rt)
#pragma unroll
      for (int ct = 0; ct < 2; ++ct) accO[rt][ct] = (floatx4){0.f, 0.f, 0.f, 0.f};
    float rs[4] = {0.f, 0.f, 0.f, 0.f};
    if (t < 64) rowsum[t] = 0.f;  // chunk-0 barrier orders this before any atomicAdd

#pragma unroll 1
    for (int mc = 0; mc < MP_ / 64; ++mc) {
      int mb0 = mc * 64;

      // ---- S = Q @ mem^T for this wave's rows x m-half ----
      floatx4 accS[2];
      accS[0] = (floatx4){0.f, 0.f, 0.f, 0.f};
      accS[1] = (floatx4){0.f, 0.f, 0.f, 0.f};
      {
        const unsigned short* bp = memb + (size_t)(mb0 + mh * 32 + lm) * C_ + quad * 8;
#pragma unroll
        for (int mt2 = 0; mt2 < 2; ++mt2) {
#pragma unroll
          for (int kb = 0; kb < 8; ++kb) {
            short8 bf = *(const short8*)(bp + (size_t)mt2 * 16 * C_ + kb * 32);
            accS[mt2] = __builtin_amdgcn_mfma_f32_16x16x32_bf16(afrag[kb], bf, accS[mt2], 0, 0, 0);
          }
        }
      }

      // ---- P = exp(S/T) bf16 (unnormalized; |logit|<=33.3), rowsum from rounded P ----
      unsigned short* P = (mc & 1) ? Pb1 : Pb0;
#pragma unroll
      for (int mt2 = 0; mt2 < 2; ++mt2) {
        int m = mb0 + mh * 32 + mt2 * 16 + lm;
        bool valid = (m < M_);
#pragma unroll
        for (int r = 0; r < 4; ++r) {
          float p = valid ? __expf(accS[mt2][r] * INV_TEMP) : 0.f;
          unsigned short pb = f2bf(p);
          rs[r] += bf2f(pb);
          P[(16 * rg + quad * 4 + r) * 72 + mh * 32 + mt2 * 16 + lm] = pb;
        }
      }
      __syncthreads();  // single barrier per chunk (P double-buffered)

      // ---- O += P @ mem for this wave's C-slice ----
#pragma unroll
      for (int ct = 0; ct < 2; ++ct) {
        int c = w * 32 + ct * 16 + lm;
        const unsigned short* tp = membT + (size_t)c * MP_ + mb0 + quad * 8;
        short8 bf0 = *(const short8*)(tp);
        short8 bf1 = *(const short8*)(tp + 32);
#pragma unroll
        for (int rt = 0; rt < 4; ++rt) {
          short8 pf0 = *(const short8*)&P[(rt * 16 + lm) * 72 + quad * 8];
          short8 pf1 = *(const short8*)&P[(rt * 16 + lm) * 72 + 32 + quad * 8];
          accO[rt][ct] = __builtin_amdgcn_mfma_f32_16x16x32_bf16(pf0, bf0, accO[rt][ct], 0, 0, 0);
          accO[rt][ct] = __builtin_amdgcn_mfma_f32_16x16x32_bf16(pf1, bf1, accO[rt][ct], 0, 0, 0);
        }
      }
    }

    // ---- rowsum: intra-wave shuffle, cross-wave LDS atomic, then comb = g/sum ----
#pragma unroll
    for (int off = 1; off < 16; off <<= 1)
#pragma unroll
      for (int r = 0; r < 4; ++r) rs[r] += __shfl_xor(rs[r], off, 64);
    if (lm == 0) {
#pragma unroll
      for (int r = 0; r < 4; ++r) atomicAdd(&rowsum[16 * rg + quad * 4 + r], rs[r]);
    }
    __syncthreads();
    if (t < 64) comb[t] = gp[row0 + t] / rowsum[t];
    __syncthreads();

    float sgn = pass ? -1.f : 1.f;
#pragma unroll
    for (int rt = 0; rt < 4; ++rt)
#pragma unroll
      for (int r = 0; r < 4; ++r) {
        float cf = sgn * comb[16 * rt + quad * 4 + r];
#pragma unroll
        for (int ct = 0; ct < 2; ++ct)
          res[rt][ct][r] += cf * accO[rt][ct][r];
      }
  }

  // ---- epilogue: out = feats*invn + res, via LDS transpose, coalesced single write ----
  int bb = row0 >> 12, hw0 = row0 & 4095;
  float* trans = (float*)smem;  // [64][67] f32 = 17152 B, aliases P buffers
  int hw = l;
  float iv = invn[row0 + hw];
  size_t ob = (size_t)bb * (size_t)C_ * HW_ + hw0 + hw;
#pragma unroll 1
  for (int cg2 = 0; cg2 < 4; ++cg2) {
    if ((w >> 1) == cg2) {
#pragma unroll
      for (int rt = 0; rt < 4; ++rt)
#pragma unroll
        for (int ct = 0; ct < 2; ++ct)
#pragma unroll
          for (int r = 0; r < 4; ++r)
            trans[(16 * rt + quad * 4 + r) * 67 + (w & 1) * 32 + ct * 16 + lm] = res[rt][ct][r];
    }
    __syncthreads();
#pragma unroll
    for (int i = 0; i < 8; ++i) {
      int cl = w * 8 + i;
      int cg = cg2 * 64 + cl;
      out[ob + (size_t)cg * HW_] = feats[ob + (size_t)cg * HW_] * iv + trans[hw * 67 + cl];
    }
    __syncthreads();
  }
}

extern "C" void kernel_launch(void* const* d_in, const int* in_sizes, int n_in,
                              void* d_out, int out_size, void* d_ws, size_t ws_size,
                              hipStream_t stream) {
  const float* feats = (const float*)d_in[0];
  const float* fg    = (const float*)d_in[1];
  const float* bg    = (const float*)d_in[2];
  const float* w1f   = (const float*)d_in[3];
  const float* b1f   = (const float*)d_in[4];
  const float* w2f   = (const float*)d_in[5];
  const float* b2f   = (const float*)d_in[6];
  const float* w1b   = (const float*)d_in[7];
  const float* b1b   = (const float*)d_in[8];
  const float* w2b   = (const float*)d_in[9];
  const float* b2b   = (const float*)d_in[10];
  float* out = (float*)d_out;

  char* ws = (char*)d_ws;
  unsigned short* xnb = (unsigned short*)ws;                 // N_*C_ bf16
  unsigned short* fgb = xnb + (size_t)N_ * C_;               // MP_*C_
  unsigned short* bgb = fgb + (size_t)MP_ * C_;
  unsigned short* fgT = bgb + (size_t)MP_ * C_;              // C_*MP_
  unsigned short* bgT = fgT + (size_t)C_ * MP_;
  float* gf   = (float*)(bgT + (size_t)C_ * MP_);            // N_
  float* gb   = gf + N_;                                     // N_
  float* invn = gb + N_;                                     // N_

  norm_mem_kernel<<<64, 256, 0, stream>>>(fg, bg, fgb, bgb, fgT, bgT);
  invnorm_x_kernel<<<N_ / 64, 256, 0, stream>>>(feats, invn);
  xnb_kernel<<<2048, 256, 0, stream>>>(feats, invn, xnb);
  gate_kernel<<<N_ / 16, 256, 0, stream>>>(xnb, w1f, b1f, w2f, b2f,
                                           w1b, b1b, w2b, b2b, gf, gb);
  flash_fused_kernel<<<N_ / 64, 512, 0, stream>>>(
      xnb, fgb, fgT, bgb, bgT, gf, gb, feats, invn, out);
}

// Round 4
// 777.443 us; speedup vs baseline: 3.3372x; 1.0440x over previous
//
#include <hip/hip_runtime.h>
#include <math.h>

#define B_   8
#define C_   256
#define HW_  4096
#define N_   32768   // B_*HW_
#define M_   2024
#define MP_  2048    // M padded to multiple of 64
#define CH_  64
#define INV_TEMP 33.333333333333336f
#define NEPS 1e-12f

typedef __attribute__((ext_vector_type(8))) short short8;   // 8 x bf16 (4 VGPRs)
typedef __attribute__((ext_vector_type(4))) float floatx4;  // MFMA accumulator

__device__ __forceinline__ float wred64(float s) {
#pragma unroll
  for (int off = 32; off > 0; off >>= 1) s += __shfl_xor(s, off, 64);
  return s;
}

__device__ __forceinline__ unsigned short f2bf(float f) {
  union { float f; unsigned u; } v; v.f = f;
  unsigned r = v.u + 0x7FFFu + ((v.u >> 16) & 1u);  // RNE, finite inputs only
  return (unsigned short)(r >> 16);
}
__device__ __forceinline__ float bf2f(unsigned short b) {
  union { unsigned u; float f; } v; v.u = ((unsigned)b) << 16; return v.f;
}

// ------- normalize memory rows -> bf16 [MP_][C_] AND bf16-transposed [C_][MP_] -------
__global__ __launch_bounds__(256) void norm_mem_kernel(
    const float* __restrict__ fg, const float* __restrict__ bg,
    unsigned short* __restrict__ fgb, unsigned short* __restrict__ bgb,
    unsigned short* __restrict__ fgT, unsigned short* __restrict__ bgT) {
  __shared__ unsigned short tile[64][258];
  int bid = blockIdx.x;  // 0..63: 32 fg tiles then 32 bg tiles
  const float* src; unsigned short *mb, *mt; int r0;
  if (bid < 32) { src = fg; mb = fgb; mt = fgT; r0 = bid * 64; }
  else          { src = bg; mb = bgb; mt = bgT; r0 = (bid - 32) * 64; }
  int t = threadIdx.x;
  int rr = t >> 2, c4 = t & 3;
  int row = r0 + rr;
  float v[64];
  float s = 0.f;
  if (row < M_) {
    const float4* p = (const float4*)(src + (size_t)row * C_ + c4 * 64);
#pragma unroll
    for (int i = 0; i < 16; ++i) {
      float4 q = p[i];
      v[i * 4 + 0] = q.x; v[i * 4 + 1] = q.y; v[i * 4 + 2] = q.z; v[i * 4 + 3] = q.w;
      s += q.x * q.x + q.y * q.y + q.z * q.z + q.w * q.w;
    }
  } else {
#pragma unroll
    for (int i = 0; i < 64; ++i) v[i] = 0.f;
  }
  s += __shfl_xor(s, 1, 64);
  s += __shfl_xor(s, 2, 64);
  float inv = (row < M_) ? 1.0f / fmaxf(sqrtf(s), NEPS) : 0.f;
#pragma unroll
  for (int i = 0; i < 16; ++i) {
    ushort4 o;
    o.x = f2bf(v[i * 4 + 0] * inv); o.y = f2bf(v[i * 4 + 1] * inv);
    o.z = f2bf(v[i * 4 + 2] * inv); o.w = f2bf(v[i * 4 + 3] * inv);
    *(ushort4*)&mb[(size_t)row * C_ + c4 * 64 + i * 4] = o;
    *(ushort4*)&tile[rr][c4 * 64 + i * 4] = o;
  }
  __syncthreads();
  int m = t & 63, cw = t >> 6;
#pragma unroll 8
  for (int j = 0; j < 64; ++j) {
    int c = cw * 64 + j;
    mt[(size_t)c * MP_ + r0 + m] = tile[m][c];
  }
}

// ---------------- per-pixel inverse L2 norm over channels ----------------
__global__ __launch_bounds__(256) void invnorm_x_kernel(
    const float* __restrict__ feats, float* __restrict__ invn) {
  __shared__ float part[4][64];
  int t = threadIdx.x, lane = t & 63, w = t >> 6;
  int n0 = blockIdx.x * 64;
  int b = n0 >> 12, hw0 = n0 & 4095;
  const float* p = feats + (size_t)b * C_ * HW_ + hw0 + lane;
  float s = 0.f;
#pragma unroll 8
  for (int i = 0; i < 64; ++i) {
    float v = p[(size_t)(w * 64 + i) * HW_];
    s += v * v;
  }
  part[w][lane] = s;
  __syncthreads();
  if (t < 64) {
    float tot = part[0][t] + part[1][t] + part[2][t] + part[3][t];
    invn[n0 + t] = 1.0f / fmaxf(sqrtf(tot), NEPS);
  }
}

// ------- build xnb bf16 [N,C] (pixel-major) from feats (channel-major) -------
__global__ __launch_bounds__(256) void xnb_kernel(
    const float* __restrict__ feats, const float* __restrict__ invn,
    unsigned short* __restrict__ xnb) {
  __shared__ float tile[64][65];
  int ct = blockIdx.x & 3, hwt = (blockIdx.x >> 2) & 63, b = blockIdx.x >> 8;
  int c0 = ct * 64, hw0 = hwt * 64;
  int t = threadIdx.x;
  int hwl = t & 63, cw = t >> 6;
  size_t base = (size_t)b * C_ * HW_;
  int n0 = b * HW_ + hw0;
  float iv = invn[n0 + hwl];
#pragma unroll 4
  for (int i = 0; i < 16; ++i) {
    int cl = cw * 16 + i;
    tile[cl][hwl] = feats[base + (size_t)(c0 + cl) * HW_ + hw0 + hwl] * iv;
  }
  __syncthreads();
  int cl = t & 63, hp = t >> 6;
#pragma unroll 4
  for (int i = 0; i < 16; ++i) {
    int hh = hp * 16 + i;
    xnb[(size_t)(n0 + hh) * C_ + c0 + cl] = f2bf(tile[cl][hh]);
  }
}

// ---------------- gates: 16 pixels per block ----------------
__global__ __launch_bounds__(256) void gate_kernel(
    const unsigned short* __restrict__ xnb,
    const float* __restrict__ w1f, const float* __restrict__ b1f,
    const float* __restrict__ w2f, const float* __restrict__ b2f,
    const float* __restrict__ w1b, const float* __restrict__ b1b,
    const float* __restrict__ w2b, const float* __restrict__ b2b,
    float* __restrict__ gf, float* __restrict__ gb) {
  __shared__ float xr[16][C_];
  int t = threadIdx.x, w = t >> 6, lane = t & 63;
  int n0 = blockIdx.x * 16;
#pragma unroll
  for (int pp = 0; pp < 4; ++pp) {
    int px = w * 4 + pp;
    ushort4 u = *(const ushort4*)&xnb[(size_t)(n0 + px) * C_ + lane * 4];
    xr[px][lane * 4 + 0] = bf2f(u.x);
    xr[px][lane * 4 + 1] = bf2f(u.y);
    xr[px][lane * 4 + 2] = bf2f(u.z);
    xr[px][lane * 4 + 3] = bf2f(u.w);
  }
  __syncthreads();
  float hf[4], hb[4];
#pragma unroll
  for (int pp = 0; pp < 4; ++pp) { hf[pp] = b1f[lane]; hb[pp] = b1b[lane]; }
#pragma unroll 4
  for (int c = 0; c < C_; ++c) {
    float wf = w1f[c * CH_ + lane];
    float wb = w1b[c * CH_ + lane];
#pragma unroll
    for (int pp = 0; pp < 4; ++pp) {
      float x = xr[w * 4 + pp][c];
      hf[pp] += x * wf;
      hb[pp] += x * wb;
    }
  }
  float b2fv = b2f[0], b2bv = b2b[0];
#pragma unroll
  for (int pp = 0; pp < 4; ++pp) {
    float sf = fmaxf(hf[pp], 0.f) * w2f[lane];
    float sb = fmaxf(hb[pp], 0.f) * w2b[lane];
    sf = wred64(sf);
    sb = wred64(sb);
    if (lane == 0) {
      gf[n0 + w * 4 + pp] = 1.f / (1.f + __expf(-(sf + b2fv)));
      gb[n0 + w * 4 + pp] = 1.f / (1.f + __expf(-(sb + b2bv)));
    }
  }
}

// ---------------- fused MFMA flash attention v3 ----------------
// 64 pixels/block, 8 waves, target 2 blocks/CU (launch_bounds(512,4)).
// Per m-chunk: memb chunk staged to LDS (XOR-swizzled 16B units: phys_col16 =
// col16 ^ (row&7) -> ds_*_b128 stay 16B-aligned AND conflict-free); S-phase
// B-frags from LDS (kills the 4x duplicated L2 loads); P tiles swizzled the
// same way (round-3 P reads were 8-way conflicted). Next-chunk stage loads
// issue before PV (one full PV phase of latency hiding). fg pass writes its
// scaled result straight to out (no res registers -> ~115 VGPRs, 2 blocks/CU);
// bg epilogue: out = feats*invn + out - alpha_b * O_b.
__global__ __launch_bounds__(512, 4) void flash_fused_kernel(
    const unsigned short* __restrict__ xnb,
    const unsigned short* __restrict__ fgb, const unsigned short* __restrict__ fgT,
    const unsigned short* __restrict__ bgb, const unsigned short* __restrict__ bgT,
    const float* __restrict__ gf, const float* __restrict__ gb,
    const float* __restrict__ feats, const float* __restrict__ invn,
    float* __restrict__ out) {
  __shared__ __align__(16) char smem[49664];
  float* rowsum = (float*)smem;                                  // [64]
  float* comb   = (float*)(smem + 256);                          // [64]
  unsigned short* mtile = (unsigned short*)(smem + 512);         // 64 rows x 256 u16 (swizzled)
  unsigned short* Pbuf0 = (unsigned short*)(smem + 33280);       // 64 rows x 64 u16 (swizzled)
  unsigned short* Pbuf1 = (unsigned short*)(smem + 41472);
  float* trans = (float*)(smem + 512);                           // [64][67] f32, aliases mtile

  int t = threadIdx.x;
  int w = t >> 6, l = t & 63;
  int lm = l & 15, quad = l >> 4;
  int rg = w & 3, mh = w >> 2;
  int row0 = blockIdx.x * 64;

  // staging geometry: li = ro*512 + t -> row = li>>5, col16 = li&31
  int srow[4], scol[4];
#pragma unroll
  for (int ro = 0; ro < 4; ++ro) {
    int li = ro * 512 + t;
    srow[ro] = li >> 5;
    scol[ro] = li & 31;
  }

  // A-frags: rows row0 + 16*rg + lm, k = kb*32 + quad*8 + j
  short8 afrag[8];
  {
    const unsigned short* ap = xnb + (size_t)(row0 + 16 * rg + lm) * C_ + quad * 8;
#pragma unroll
    for (int kb = 0; kb < 8; ++kb)
      afrag[kb] = *(const short8*)(ap + kb * 32);
  }

  int bb = row0 >> 12, hw0 = row0 & 4095;
  float iv = invn[row0 + l];
  size_t ob = (size_t)bb * (size_t)C_ * HW_ + hw0 + l;

#pragma unroll
  for (int pass = 0; pass < 2; ++pass) {
    const unsigned short* memb  = pass ? bgb : fgb;
    const unsigned short* membT = pass ? bgT : fgT;
    const float* gp = pass ? gb : gf;

    floatx4 accO[4][2];
#pragma unroll
    for (int rt = 0; rt < 4; ++rt)
#pragma unroll
      for (int ct = 0; ct < 2; ++ct) accO[rt][ct] = (floatx4){0.f, 0.f, 0.f, 0.f};
    float rs[4] = {0.f, 0.f, 0.f, 0.f};
    if (t < 64) rowsum[t] = 0.f;  // ordered before use by chunk-0 barriers

    // stage chunk 0 into regs
    float4 sv[4];
#pragma unroll
    for (int ro = 0; ro < 4; ++ro)
      sv[ro] = *(const float4*)&memb[(size_t)srow[ro] * C_ + scol[ro] * 8];

#pragma unroll 1
    for (int mc = 0; mc < MP_ / 64; ++mc) {
      int mb0 = mc * 64;

      // ---- write staged chunk to LDS (swizzled, 16B-aligned, conflict-free) ----
#pragma unroll
      for (int ro = 0; ro < 4; ++ro) {
        int idx = srow[ro] * 256 + ((scol[ro] ^ (srow[ro] & 7)) << 3);
        *(float4*)&mtile[idx] = sv[ro];
      }
      __syncthreads();  // A: mtile ready

      // ---- S = Q @ mem^T, B-frags from LDS ----
      floatx4 accS[2];
      accS[0] = (floatx4){0.f, 0.f, 0.f, 0.f};
      accS[1] = (floatx4){0.f, 0.f, 0.f, 0.f};
#pragma unroll
      for (int mt2 = 0; mt2 < 2; ++mt2) {
        int mrow = mh * 32 + mt2 * 16 + lm;
        int swz = mrow & 7;
        int base = mrow * 256;
#pragma unroll
        for (int kb = 0; kb < 8; ++kb) {
          short8 bf = *(const short8*)&mtile[base + (((kb * 4 + quad) ^ swz) << 3)];
          accS[mt2] = __builtin_amdgcn_mfma_f32_16x16x32_bf16(afrag[kb], bf, accS[mt2], 0, 0, 0);
        }
      }

      // ---- prefetch PV B-frags (membT, global; hidden under exp + barrier) ----
      short8 bfT[2][2];
#pragma unroll
      for (int ct = 0; ct < 2; ++ct) {
        int c = w * 32 + ct * 16 + lm;
        const unsigned short* tp = membT + (size_t)c * MP_ + mb0 + quad * 8;
        bfT[ct][0] = *(const short8*)(tp);
        bfT[ct][1] = *(const short8*)(tp + 32);
      }

      // ---- P = exp(S/T) bf16 (unnormalized; |logit|<=33.3), swizzled store ----
      unsigned short* P = (mc & 1) ? Pbuf1 : Pbuf0;
#pragma unroll
      for (int mt2 = 0; mt2 < 2; ++mt2) {
        int m = mh * 32 + mt2 * 16 + lm;
        bool valid = (mb0 + m < M_);
#pragma unroll
        for (int r = 0; r < 4; ++r) {
          float p = valid ? __expf(accS[mt2][r] * INV_TEMP) : 0.f;
          unsigned short pb = f2bf(p);
          rs[r] += bf2f(pb);
          int prow = 16 * rg + quad * 4 + r;
          P[prow * 64 + (((m >> 3) ^ (prow & 7)) << 3) + (m & 7)] = pb;
        }
      }
      __syncthreads();  // B: P visible + mtile reads done

      // ---- issue next chunk's stage loads (in flight across PV) ----
      if (mc < MP_ / 64 - 1) {
        int nb0 = (mc + 1) * 64;
#pragma unroll
        for (int ro = 0; ro < 4; ++ro)
          sv[ro] = *(const float4*)&memb[(size_t)(nb0 + srow[ro]) * C_ + scol[ro] * 8];
      }

      // ---- O += P @ mem (this wave's 32-wide C-slice) ----
#pragma unroll
      for (int rt = 0; rt < 4; ++rt) {
        int prow = rt * 16 + lm;
        int swz = prow & 7;
        short8 pf0 = *(const short8*)&P[prow * 64 + (((0 * 4 + quad) ^ swz) << 3)];
        short8 pf1 = *(const short8*)&P[prow * 64 + (((1 * 4 + quad) ^ swz) << 3)];
#pragma unroll
        for (int ct = 0; ct < 2; ++ct) {
          accO[rt][ct] = __builtin_amdgcn_mfma_f32_16x16x32_bf16(pf0, bfT[ct][0], accO[rt][ct], 0, 0, 0);
          accO[rt][ct] = __builtin_amdgcn_mfma_f32_16x16x32_bf16(pf1, bfT[ct][1], accO[rt][ct], 0, 0, 0);
        }
      }
    }

    // ---- rowsum: intra-wave shuffle over lm, cross-wave LDS atomic ----
#pragma unroll
    for (int off = 1; off < 16; off <<= 1)
#pragma unroll
      for (int r = 0; r < 4; ++r) rs[r] += __shfl_xor(rs[r], off, 64);
    if (lm == 0) {
#pragma unroll
      for (int r = 0; r < 4; ++r) atomicAdd(&rowsum[16 * rg + quad * 4 + r], rs[r]);
    }
    __syncthreads();
    if (t < 64) comb[t] = gp[row0 + t] / rowsum[t];
    __syncthreads();

    // ---- epilogue (trans aliases mtile; no stage loads in flight here) ----
#pragma unroll 1
    for (int cg2 = 0; cg2 < 4; ++cg2) {
      if ((w >> 1) == cg2) {
#pragma unroll
        for (int rt = 0; rt < 4; ++rt)
#pragma unroll
          for (int r = 0; r < 4; ++r) {
            float cf = comb[16 * rt + quad * 4 + r];
#pragma unroll
            for (int ct = 0; ct < 2; ++ct)
              trans[(16 * rt + quad * 4 + r) * 67 + (w & 1) * 32 + ct * 16 + lm] =
                  cf * accO[rt][ct][r];
          }
      }
      __syncthreads();
      if (pass == 0) {
#pragma unroll
        for (int i = 0; i < 8; ++i) {
          int cl = w * 8 + i;
          int cg = cg2 * 64 + cl;
          out[ob + (size_t)cg * HW_] = trans[l * 67 + cl];  // out = alpha_f * O_f
        }
      } else {
#pragma unroll
        for (int i = 0; i < 8; ++i) {
          int cl = w * 8 + i;
          int cg = cg2 * 64 + cl;
          size_t a = ob + (size_t)cg * HW_;
          out[a] = feats[a] * iv + out[a] - trans[l * 67 + cl];
        }
      }
      __syncthreads();
    }
  }
}

extern "C" void kernel_launch(void* const* d_in, const int* in_sizes, int n_in,
                              void* d_out, int out_size, void* d_ws, size_t ws_size,
                              hipStream_t stream) {
  const float* feats = (const float*)d_in[0];
  const float* fg    = (const float*)d_in[1];
  const float* bg    = (const float*)d_in[2];
  const float* w1f   = (const float*)d_in[3];
  const float* b1f   = (const float*)d_in[4];
  const float* w2f   = (const float*)d_in[5];
  const float* b2f   = (const float*)d_in[6];
  const float* w1b   = (const float*)d_in[7];
  const float* b1b   = (const float*)d_in[8];
  const float* w2b   = (const float*)d_in[9];
  const float* b2b   = (const float*)d_in[10];
  float* out = (float*)d_out;

  char* ws = (char*)d_ws;
  unsigned short* xnb = (unsigned short*)ws;                 // N_*C_ bf16
  unsigned short* fgb = xnb + (size_t)N_ * C_;               // MP_*C_
  unsigned short* bgb = fgb + (size_t)MP_ * C_;
  unsigned short* fgT = bgb + (size_t)MP_ * C_;              // C_*MP_
  unsigned short* bgT = fgT + (size_t)C_ * MP_;
  float* gf   = (float*)(bgT + (size_t)C_ * MP_);            // N_
  float* gb   = gf + N_;                                     // N_
  float* invn = gb + N_;                                     // N_

  norm_mem_kernel<<<64, 256, 0, stream>>>(fg, bg, fgb, bgb, fgT, bgT);
  invnorm_x_kernel<<<N_ / 64, 256, 0, stream>>>(feats, invn);
  xnb_kernel<<<2048, 256, 0, stream>>>(feats, invn, xnb);
  gate_kernel<<<N_ / 16, 256, 0, stream>>>(xnb, w1f, b1f, w2f, b2f,
                                           w1b, b1b, w2b, b2b, gf, gb);
  flash_fused_kernel<<<N_ / 64, 512, 0, stream>>>(
      xnb, fgb, fgT, bgb, bgT, gf, gb, feats, invn, out);
}

// Round 5
// 344.886 us; speedup vs baseline: 7.5228x; 2.2542x over previous
//
#include <hip/hip_runtime.h>
#include <math.h>

#define B_   8
#define C_   256
#define HW_  4096
#define N_   32768   // B_*HW_
#define M_   2024
#define MP_  2048    // M padded to multiple of 64
#define CH_  64
#define NCHUNK (MP_ / 64)  // 32
#define INV_TEMP 33.333333333333336f
#define NEPS 1e-12f

typedef __attribute__((ext_vector_type(8))) short short8;   // 8 x bf16 (4 VGPRs)
typedef __attribute__((ext_vector_type(4))) float floatx4;  // MFMA accumulator

__device__ __forceinline__ float wred64(float s) {
#pragma unroll
  for (int off = 32; off > 0; off >>= 1) s += __shfl_xor(s, off, 64);
  return s;
}

__device__ __forceinline__ unsigned short f2bf(float f) {
  union { float f; unsigned u; } v; v.f = f;
  unsigned r = v.u + 0x7FFFu + ((v.u >> 16) & 1u);  // RNE, finite inputs only
  return (unsigned short)(r >> 16);
}
__device__ __forceinline__ float bf2f(unsigned short b) {
  union { unsigned u; float f; } v; v.u = ((unsigned)b) << 16; return v.f;
}

// raw workgroup barrier that does NOT drain vmcnt (keeps global_load_lds
// prefetch in flight across it) — CK/AITER idiom.
__device__ __forceinline__ void barrier_lds_only() {
  asm volatile("s_waitcnt lgkmcnt(0)\n\ts_barrier" ::: "memory");
}

// async 16B/lane global->LDS copy; LDS dest = wave-uniform base + lane*16.
__device__ __forceinline__ void async_copy16(const unsigned short* gsrc,
                                             unsigned short* lds) {
  __builtin_amdgcn_global_load_lds(
      (const __attribute__((address_space(1))) void*)gsrc,
      (__attribute__((address_space(3))) void*)lds, 16, 0, 0);
}

// ---- normalize memory rows -> memS (MFMA B-frag order) + membT [C][MP] ----
// memS element (m, c): unit = ((m>>6)*32 + (c>>5)*4 + ((c>>3)&3))*64 + (m&63),
// u16 index = unit*8 + (c&7). A 64-row chunk is a contiguous 32 KB block that
// the flash kernel copies to LDS verbatim via global_load_lds.
__global__ __launch_bounds__(256) void norm_mem_kernel(
    const float* __restrict__ fg, const float* __restrict__ bg,
    unsigned short* __restrict__ fgS, unsigned short* __restrict__ bgS,
    unsigned short* __restrict__ fgT, unsigned short* __restrict__ bgT) {
  __shared__ unsigned short tile[64][258];
  int bid = blockIdx.x;  // 0..63: 32 fg chunks then 32 bg chunks
  const float* src; unsigned short *ms, *mt; int r0;
  if (bid < 32) { src = fg; ms = fgS; mt = fgT; r0 = bid * 64; }
  else          { src = bg; ms = bgS; mt = bgT; r0 = (bid - 32) * 64; }
  int t = threadIdx.x;
  int rr = t >> 2, c4 = t & 3;  // row r0+rr, channel quarter c4
  int row = r0 + rr;
  int chunk = r0 >> 6;
  float v[64];
  float s = 0.f;
  if (row < M_) {
    const float4* p = (const float4*)(src + (size_t)row * C_ + c4 * 64);
#pragma unroll
    for (int i = 0; i < 16; ++i) {
      float4 q = p[i];
      v[i * 4 + 0] = q.x; v[i * 4 + 1] = q.y; v[i * 4 + 2] = q.z; v[i * 4 + 3] = q.w;
      s += q.x * q.x + q.y * q.y + q.z * q.z + q.w * q.w;
    }
  } else {
#pragma unroll
    for (int i = 0; i < 64; ++i) v[i] = 0.f;  // zero padding rows
  }
  s += __shfl_xor(s, 1, 64);
  s += __shfl_xor(s, 2, 64);
  float inv = (row < M_) ? 1.0f / fmaxf(sqrtf(s), NEPS) : 0.f;
#pragma unroll
  for (int i = 0; i < 16; ++i) {
    int c = c4 * 64 + i * 4;
    ushort4 o;
    o.x = f2bf(v[i * 4 + 0] * inv); o.y = f2bf(v[i * 4 + 1] * inv);
    o.z = f2bf(v[i * 4 + 2] * inv); o.w = f2bf(v[i * 4 + 3] * inv);
    int unit = (chunk * 32 + (c >> 5) * 4 + ((c >> 3) & 3)) * 64 + rr;
    *(ushort4*)&ms[(size_t)unit * 8 + (c & 7)] = o;
    *(ushort4*)&tile[rr][c] = o;
  }
  __syncthreads();
  int m = t & 63, cw = t >> 6;
#pragma unroll 8
  for (int j = 0; j < 64; ++j) {
    int c = cw * 64 + j;
    mt[(size_t)c * MP_ + r0 + m] = tile[m][c];
  }
}

// ---- fused per-pixel inv-norm + xnb bf16 [N,C] build (one feats pass) ----
__global__ __launch_bounds__(256) void prep_x_kernel(
    const float* __restrict__ feats, float* __restrict__ invn,
    unsigned short* __restrict__ xnb) {
  __shared__ unsigned short tileb[256][66];
  __shared__ float part[4][64];
  __shared__ float invs[64];
  int t = threadIdx.x, hwl = t & 63, cw = t >> 6;
  int n0 = blockIdx.x * 64;
  int b = n0 >> 12, hw0 = n0 & 4095;
  const float* p = feats + (size_t)b * C_ * HW_ + hw0 + hwl;
  float s = 0.f;
#pragma unroll 8
  for (int i = 0; i < 64; ++i) {
    int c = cw * 64 + i;
    float v = p[(size_t)c * HW_];
    s += v * v;
    tileb[c][hwl] = f2bf(v);
  }
  part[cw][hwl] = s;
  __syncthreads();
  if (t < 64) {
    float tot = part[0][t] + part[1][t] + part[2][t] + part[3][t];
    float inv = 1.0f / fmaxf(sqrtf(tot), NEPS);
    invn[n0 + t] = inv;
    invs[t] = inv;
  }
  __syncthreads();
  int px = t >> 2, q = t & 3;
  float iv = invs[px];
  unsigned short* xp = xnb + (size_t)(n0 + px) * C_;
#pragma unroll
  for (int blk = 0; blk < 8; ++blk) {
    int cb = blk * 4 + q;  // 4 q-lanes -> 64 B contiguous stores
    short8 o;
#pragma unroll
    for (int j = 0; j < 8; ++j)
      o[j] = (short)f2bf(bf2f(tileb[cb * 8 + j][px]) * iv);
    *(short8*)&xp[cb * 8] = o;
  }
}

// ---------------- gates: 16 pixels per block ----------------
__global__ __launch_bounds__(256) void gate_kernel(
    const unsigned short* __restrict__ xnb,
    const float* __restrict__ w1f, const float* __restrict__ b1f,
    const float* __restrict__ w2f, const float* __restrict__ b2f,
    const float* __restrict__ w1b, const float* __restrict__ b1b,
    const float* __restrict__ w2b, const float* __restrict__ b2b,
    float* __restrict__ gf, float* __restrict__ gb) {
  __shared__ float xr[16][C_];
  int t = threadIdx.x, w = t >> 6, lane = t & 63;
  int n0 = blockIdx.x * 16;
#pragma unroll
  for (int pp = 0; pp < 4; ++pp) {
    int px = w * 4 + pp;
    ushort4 u = *(const ushort4*)&xnb[(size_t)(n0 + px) * C_ + lane * 4];
    xr[px][lane * 4 + 0] = bf2f(u.x);
    xr[px][lane * 4 + 1] = bf2f(u.y);
    xr[px][lane * 4 + 2] = bf2f(u.z);
    xr[px][lane * 4 + 3] = bf2f(u.w);
  }
  __syncthreads();
  float hf[4], hb[4];
#pragma unroll
  for (int pp = 0; pp < 4; ++pp) { hf[pp] = b1f[lane]; hb[pp] = b1b[lane]; }
#pragma unroll 4
  for (int c = 0; c < C_; ++c) {
    float wf = w1f[c * CH_ + lane];
    float wb = w1b[c * CH_ + lane];
#pragma unroll
    for (int pp = 0; pp < 4; ++pp) {
      float x = xr[w * 4 + pp][c];
      hf[pp] += x * wf;
      hb[pp] += x * wb;
    }
  }
  float b2fv = b2f[0], b2bv = b2b[0];
#pragma unroll
  for (int pp = 0; pp < 4; ++pp) {
    float sf = fmaxf(hf[pp], 0.f) * w2f[lane];
    float sb = fmaxf(hb[pp], 0.f) * w2b[lane];
    sf = wred64(sf);
    sb = wred64(sb);
    if (lane == 0) {
      gf[n0 + w * 4 + pp] = 1.f / (1.f + __expf(-(sf + b2fv)));
      gb[n0 + w * 4 + pp] = 1.f / (1.f + __expf(-(sb + b2bv)));
    }
  }
}

// stage one 32 KB memS chunk into mtile (contiguous copy, no VGPR round-trip)
__device__ __forceinline__ void stage_chunk(const unsigned short* memS, int mc,
                                            unsigned short* mtile, int w, int l) {
  const unsigned short* src = memS + (size_t)mc * 16384;
#pragma unroll
  for (int it = 0; it < 4; ++it) {
    int seg = (it * 8 + w) * 512;  // u16 units; 64 lanes x 16 B = 1 KB/wave/iter
    async_copy16(src + seg + l * 8, mtile + seg);
  }
}

// ---------------- fused MFMA flash attention v4 ----------------
// 64 pixels/block, 8 waves, 2 blocks/CU. memS pre-arranged in B-frag order ->
// LDS staging is a verbatim global_load_lds copy (0 VGPRs, conflict-free
// reads). P tiles in A-frag order (conflict-free b128 reads). Raw
// lgkm-only barrier after P-write keeps the next chunk's load_lds in flight;
// the __syncthreads at chunk top is the only vmcnt drain.
__global__ __launch_bounds__(512, 4) void flash_fused_kernel(
    const unsigned short* __restrict__ xnb,
    const unsigned short* __restrict__ fgS, const unsigned short* __restrict__ fgT,
    const unsigned short* __restrict__ bgS, const unsigned short* __restrict__ bgT,
    const float* __restrict__ gf, const float* __restrict__ gb,
    const float* __restrict__ feats, const float* __restrict__ invn,
    float* __restrict__ out) {
  __shared__ __align__(16) char smem[49664];
  unsigned short* mtile = (unsigned short*)smem;            // 32 KB frag-order chunk
  unsigned short* Pbuf0 = (unsigned short*)(smem + 32768);  // 8 KB: unit=(g*64+prow)
  unsigned short* Pbuf1 = (unsigned short*)(smem + 40960);  // 8 KB
  float* rowsum = (float*)(smem + 49152);                   // [64]
  float* comb   = (float*)(smem + 49408);                   // [64]
  float* trans  = (float*)smem;                             // [64][67] f32, aliases mtile

  int t = threadIdx.x;
  int w = t >> 6, l = t & 63;
  int lm = l & 15, quad = l >> 4;
  int rg = w & 3, mh = w >> 2;
  int row0 = blockIdx.x * 64;

  // A-frags: rows row0 + 16*rg + lm (waves rg and rg+4 duplicate)
  short8 afrag[8];
  {
    const unsigned short* ap = xnb + (size_t)(row0 + 16 * rg + lm) * C_ + quad * 8;
#pragma unroll
    for (int kb = 0; kb < 8; ++kb)
      afrag[kb] = *(const short8*)(ap + kb * 32);
  }

  int bb = row0 >> 12, hw0 = row0 & 4095;
  float iv = invn[row0 + l];
  size_t ob = (size_t)bb * (size_t)C_ * HW_ + hw0 + l;

#pragma unroll 1
  for (int pass = 0; pass < 2; ++pass) {
    const unsigned short* memS  = pass ? bgS : fgS;
    const unsigned short* membT = pass ? bgT : fgT;
    const float* gp = pass ? gb : gf;

    floatx4 accO[4][2];
#pragma unroll
    for (int rt = 0; rt < 4; ++rt)
#pragma unroll
      for (int ct = 0; ct < 2; ++ct) accO[rt][ct] = (floatx4){0.f, 0.f, 0.f, 0.f};
    float rs[4] = {0.f, 0.f, 0.f, 0.f};
    if (t < 64) rowsum[t] = 0.f;  // ordered before atomics by chunk barriers

    stage_chunk(memS, 0, mtile, w, l);

#pragma unroll 1
    for (int mc = 0; mc < NCHUNK; ++mc) {
      __syncthreads();  // A: drains vmcnt -> mtile[mc] ready for all waves

      // PV B-frags for this chunk (global, read-once; hidden under S-phase)
      short8 bfT[2][2];
#pragma unroll
      for (int ct = 0; ct < 2; ++ct) {
        const unsigned short* tp =
            membT + (size_t)(w * 32 + ct * 16 + lm) * MP_ + mc * 64 + quad * 8;
        bfT[ct][0] = *(const short8*)(tp);
        bfT[ct][1] = *(const short8*)(tp + 32);
      }

      // ---- S = Q @ mem^T (rows 16rg.., m-half mh) from LDS frag-order tile ----
      floatx4 accS[2];
      accS[0] = (floatx4){0.f, 0.f, 0.f, 0.f};
      accS[1] = (floatx4){0.f, 0.f, 0.f, 0.f};
#pragma unroll
      for (int mt2 = 0; mt2 < 2; ++mt2) {
        int mrow = mh * 32 + mt2 * 16 + lm;
#pragma unroll
        for (int kb = 0; kb < 8; ++kb) {
          short8 bf = *(const short8*)&mtile[(size_t)(((kb * 4 + quad) * 64) + mrow) * 8];
          accS[mt2] = __builtin_amdgcn_mfma_f32_16x16x32_bf16(afrag[kb], bf, accS[mt2], 0, 0, 0);
        }
      }

      // ---- P = exp(S/T) bf16 (unnormalized; |logit|<=33.3), frag-order store ----
      unsigned short* P = (mc & 1) ? Pbuf1 : Pbuf0;
#pragma unroll
      for (int mt2 = 0; mt2 < 2; ++mt2) {
        int m = mh * 32 + mt2 * 16 + lm;
        bool valid = (mc * 64 + m < M_);
        int g = mh * 4 + mt2 * 2 + (lm >> 3);
#pragma unroll
        for (int r = 0; r < 4; ++r) {
          float pv = valid ? __expf(accS[mt2][r] * INV_TEMP) : 0.f;
          unsigned short pb = f2bf(pv);
          rs[r] += bf2f(pb);
          P[(g * 64 + 16 * rg + quad * 4 + r) * 8 + (lm & 7)] = pb;
        }
      }
      barrier_lds_only();  // B: P visible + mtile S-reads done (vmcnt NOT drained)

      // issue next chunk's async stage (in flight across PV, lands before next A)
      if (mc + 1 < NCHUNK) stage_chunk(memS, mc + 1, mtile, w, l);

      // ---- O += P @ mem (this wave's 32-wide C-slice) ----
#pragma unroll
      for (int rt = 0; rt < 4; ++rt) {
        short8 pf0 = *(const short8*)&P[(size_t)((0 + quad) * 64 + rt * 16 + lm) * 8];
        short8 pf1 = *(const short8*)&P[(size_t)((4 + quad) * 64 + rt * 16 + lm) * 8];
#pragma unroll
        for (int ct = 0; ct < 2; ++ct) {
          accO[rt][ct] = __builtin_amdgcn_mfma_f32_16x16x32_bf16(pf0, bfT[ct][0], accO[rt][ct], 0, 0, 0);
          accO[rt][ct] = __builtin_amdgcn_mfma_f32_16x16x32_bf16(pf1, bfT[ct][1], accO[rt][ct], 0, 0, 0);
        }
      }
    }

    // ---- rowsum: intra-wave shuffle over lm, cross-wave LDS atomic ----
#pragma unroll
    for (int off = 1; off < 16; off <<= 1)
#pragma unroll
      for (int r = 0; r < 4; ++r) rs[r] += __shfl_xor(rs[r], off, 64);
    if (lm == 0) {
#pragma unroll
      for (int r = 0; r < 4; ++r) atomicAdd(&rowsum[16 * rg + quad * 4 + r], rs[r]);
    }
    __syncthreads();
    if (t < 64) comb[t] = gp[row0 + t] / rowsum[t];
    __syncthreads();

    // ---- epilogue (trans aliases mtile; no stage loads in flight here) ----
#pragma unroll 1
    for (int cg2 = 0; cg2 < 4; ++cg2) {
      if ((w >> 1) == cg2) {
#pragma unroll
        for (int rt = 0; rt < 4; ++rt)
#pragma unroll
          for (int r = 0; r < 4; ++r) {
            float cf = comb[16 * rt + quad * 4 + r];
#pragma unroll
            for (int ct = 0; ct < 2; ++ct)
              trans[(16 * rt + quad * 4 + r) * 67 + (w & 1) * 32 + ct * 16 + lm] =
                  cf * accO[rt][ct][r];
          }
      }
      __syncthreads();
      if (pass == 0) {
#pragma unroll
        for (int i = 0; i < 8; ++i) {
          int cl = w * 8 + i;
          int cg = cg2 * 64 + cl;
          out[ob + (size_t)cg * HW_] = trans[l * 67 + cl];  // out = alpha_f * O_f
        }
      } else {
#pragma unroll
        for (int i = 0; i < 8; ++i) {
          int cl = w * 8 + i;
          int cg = cg2 * 64 + cl;
          size_t a = ob + (size_t)cg * HW_;
          out[a] = feats[a] * iv + out[a] - trans[l * 67 + cl];
        }
      }
      __syncthreads();
    }
  }
}

extern "C" void kernel_launch(void* const* d_in, const int* in_sizes, int n_in,
                              void* d_out, int out_size, void* d_ws, size_t ws_size,
                              hipStream_t stream) {
  const float* feats = (const float*)d_in[0];
  const float* fg    = (const float*)d_in[1];
  const float* bg    = (const float*)d_in[2];
  const float* w1f   = (const float*)d_in[3];
  const float* b1f   = (const float*)d_in[4];
  const float* w2f   = (const float*)d_in[5];
  const float* b2f   = (const float*)d_in[6];
  const float* w1b   = (const float*)d_in[7];
  const float* b1b   = (const float*)d_in[8];
  const float* w2b   = (const float*)d_in[9];
  const float* b2b   = (const float*)d_in[10];
  float* out = (float*)d_out;

  char* ws = (char*)d_ws;
  unsigned short* xnb = (unsigned short*)ws;                 // N_*C_ bf16
  unsigned short* fgS = xnb + (size_t)N_ * C_;               // MP_*C_ (frag order)
  unsigned short* bgS = fgS + (size_t)MP_ * C_;
  unsigned short* fgT = bgS + (size_t)MP_ * C_;              // C_*MP_
  unsigned short* bgT = fgT + (size_t)C_ * MP_;
  float* gf   = (float*)(bgT + (size_t)C_ * MP_);            // N_
  float* gb   = gf + N_;                                     // N_
  float* invn = gb + N_;                                     // N_

  norm_mem_kernel<<<64, 256, 0, stream>>>(fg, bg, fgS, bgS, fgT, bgT);
  prep_x_kernel<<<N_ / 64, 256, 0, stream>>>(feats, invn, xnb);
  gate_kernel<<<N_ / 16, 256, 0, stream>>>(xnb, w1f, b1f, w2f, b2f,
                                           w1b, b1b, w2b, b2b, gf, gb);
  flash_fused_kernel<<<N_ / 64, 512, 0, stream>>>(
      xnb, fgS, fgT, bgS, bgT, gf, gb, feats, invn, out);
}